// Round 14
// baseline (519.079 us; speedup 1.0000x reference)
//
#include <hip/hip_runtime.h>
#include <hip/hip_bf16.h>
#include <math.h>

// Problem constants
#define B_   4
#define CIN  256
#define COUT 256
#define HW   4096   // 64*64

typedef __attribute__((ext_vector_type(8))) short short8;
typedef __attribute__((ext_vector_type(4))) float float4v;

// LDS row strides (ushorts).
// LSTR2 (64-ch rows): 144 B = 36 dwords (36 mod 32 = 4 -> proven 2-way pattern).
// LSTR4 (128-ch rows): 272 B = 68 dwords (68 mod 32 = 4 -> same pattern).
#define LSTR  40
#define LSTR2 72
#define LSTR4 136

__device__ __forceinline__ float sigmoidf_(float v){ return 1.0f/(1.0f+expf(-v)); }
__device__ __forceinline__ ushort f2bf(float f){
  union { float f; unsigned u; } x; x.f = f;
  unsigned r = x.u + 0x7fffu + ((x.u>>16)&1u);
  return (ushort)(r>>16);
}
__device__ __forceinline__ float bflo(unsigned u){ union{unsigned u; float f;} c; c.u = u<<16;          return c.f; }
__device__ __forceinline__ float bfhi(unsigned u){ union{unsigned u; float f;} c; c.u = u & 0xffff0000u; return c.f; }

// ---------- transpose x [B][C][HW] -> xtb [B][HW][C] bf16 ----------
__global__ void k_transpose_x(const float* __restrict__ x, ushort* __restrict__ xtb){
  __shared__ float ts[32][33];
  int tx = threadIdx.x & 31, ty = threadIdx.x >> 5;
  int p0 = blockIdx.x * 32, c0 = blockIdx.y * 32, b = blockIdx.z;
  const float* xb = x + (size_t)b*CIN*HW;
#pragma unroll
  for(int q=0;q<4;q++){
    int c = ty + q*8;
    ts[c][tx] = xb[(size_t)(c0+c)*HW + p0+tx];
  }
  __syncthreads();
#pragma unroll
  for(int q=0;q<4;q++){
    int pr = ty + q*8;
    xtb[((size_t)(b*HW + p0+pr)<<8) + c0+tx] = f2bf(ts[tx][pr]);
  }
}

// ---------- fused weight re-layouts (bf16, K-chunked [kc][o][kk]) + stat zeroing ----------
__global__ void k_build_all(const float* __restrict__ w_off, const float* __restrict__ w_dcn,
                            const float* __restrict__ w_up,
                            ushort* __restrict__ Wob, ushort* __restrict__ Wdb,
                            ushort* __restrict__ WT2c,
                            float* __restrict__ st1raw, float* __restrict__ st2raw){
  int bid = blockIdx.x;
  if(bid == 0 && threadIdx.x < 256){
    int t = threadIdx.x;
    st1raw[t] = 0.f; st1raw[256+t] = 0.f;
    st2raw[t] = 0.f; st2raw[256+t] = 0.f;
  }
  if(bid < 288){
    int f = bid*256 + threadIdx.x;
    int kc = f>>10, o = (f>>5)&31, kk = f&31;
    int k = kc*32 + kk, tap = k>>8, c = k&255;
    float v = (o < 27) ? w_off[(size_t)o*2304 + c*9 + tap] : 0.f;
    Wob[f] = f2bf(v);
  } else if(bid < 288+2304){
    int f = (bid-288)*256 + threadIdx.x;
    int kc = f>>13, o = (f>>5)&255, kk = f&31;
    int k = kc>>3, c = ((kc&7)<<5) | kk;
    Wdb[f] = f2bf(w_dcn[(size_t)o*2304 + c*9 + k]);
  } else {
    int f = (bid-2592)*256 + threadIdx.x;
    int pp = f>>18, kc = (f>>13)&31, o = (f>>5)&255, kk = f&31;
    int k = kc*32 + kk, ab = k>>8, c = k&255;
    int a = ab>>1, bb = ab&1, ph = pp>>1, pw = pp&1;
    WT2c[f] = f2bf(w_up[(size_t)(c*COUT+o)*16 + (3-ph-2*a)*4 + (3-pw-2*bb)]);
  }
}

// ---------- offset conv MFMA: M=32(27), Nb=64 px, K-SPLIT (z-half does 9 quads) ----------
// grid (64,4,2) = 512 blocks (R13-proven). 256 thr = 4 waves, quad chunks,
// W-first JIT, 1-deep gather. Output: f32 partial om2[z][b][27][HW].
__global__ __launch_bounds__(256) void k_offset_mfma(const ushort* __restrict__ xtb,
                        const ushort* __restrict__ Wob, float* __restrict__ om2){
  __shared__ ushort Vs[2][64*LSTR4];   // 2 x 17408 B
  __shared__ int sIdx[576];
  int tid = threadIdx.x;
  int fb  = blockIdx.x + (blockIdx.y<<6);       // 0..255
  int b   = (fb&7)>>1;                          // XCD-b affinity
  int px0 = ((((fb>>3)<<1) | (fb&1))) << 6;
  int z   = blockIdx.z;                         // K-half
  for(int t=tid; t<576; t+=256){
    int tap = t>>6, px = t&63;
    int p = px0+px, hh = p>>6, ww = p&63;
    int ih = hh + tap/3 - 1, iw = ww + tap%3 - 1;
    sIdx[t] = (ih>=0 && ih<64 && iw>=0 && iw<64) ? ((b*HW + ih*64+iw)<<8) : -1;
  }
  __syncthreads();

  int lane = tid&63, wv = tid>>6, lo = lane&15, hi = lane>>4;
  float4v acc[2];
  acc[0] = acc[1] = (float4v){0.f,0.f,0.f,0.f};
  int vpx = tid>>2, vseg = tid&3;               // 64 px x 4 thr, 32 ch each
  const int wlane = lo*32 + hi*8;

#define OFF_WLOAD_ALLQ(Q, W) do{ \
    _Pragma("unroll") \
    for(int c_=0;c_<4;c_++){ \
      const ushort* wp_ = Wob + (((Q)*4+c_)<<10) + wlane; \
      W[2*c_+0] = *(const short8*)(wp_); \
      W[2*c_+1] = *(const short8*)(wp_ + 512); \
    } \
  }while(0)

#define OFF_GATHER_Q(Q, V) do{ \
    int k_ = (Q)>>1, c0_ = ((Q)&1)<<7; \
    int idx_ = sIdx[(k_<<6)+vpx]; \
    int coff_ = c0_ + (vseg<<5); \
    V[0]=make_uint4(0,0,0,0); V[1]=make_uint4(0,0,0,0); \
    V[2]=make_uint4(0,0,0,0); V[3]=make_uint4(0,0,0,0); \
    if(idx_ >= 0){ \
      V[0] = *(const uint4*)(xtb + idx_ + coff_); \
      V[1] = *(const uint4*)(xtb + idx_ + coff_ + 8); \
      V[2] = *(const uint4*)(xtb + idx_ + coff_ + 16); \
      V[3] = *(const uint4*)(xtb + idx_ + coff_ + 24); \
    } \
  }while(0)

#define OFF_VWRITE_Q(V, BUF) do{ \
    ushort* vp_ = &Vs[BUF][vpx*LSTR4 + (vseg<<5)]; \
    *(uint4*)(vp_)      = V[0]; \
    *(uint4*)(vp_ + 8)  = V[1]; \
    *(uint4*)(vp_ + 16) = V[2]; \
    *(uint4*)(vp_ + 24) = V[3]; \
  }while(0)

#define OFF_COMPUTE_Q2(W, BUF) do{ \
    const ushort* bp_ = &Vs[BUF][(wv*16+lo)*LSTR4 + hi*8]; \
    _Pragma("unroll") \
    for(int c_=0;c_<4;c_++){ \
      short8 ba_ = *(const short8*)(bp_ + c_*32); \
      acc[0] = __builtin_amdgcn_mfma_f32_16x16x32_bf16(W[2*c_+0], ba_, acc[0], 0,0,0); \
      acc[1] = __builtin_amdgcn_mfma_f32_16x16x32_bf16(W[2*c_+1], ba_, acc[1], 0,0,0); \
    } \
  }while(0)

  short8 w[8];
  uint4 vE[4];
  // ---- prologue: gather quad z*9 -> Vs[0] ----
  OFF_GATHER_Q(z*9, vE);
  OFF_VWRITE_Q(vE, 0);
  __syncthreads();

#pragma unroll 1
  for(int pc=0; pc<9; ++pc){
    int cur = pc&1;
    int q = z*9 + pc;
    OFF_WLOAD_ALLQ(q, w);                 // W first (vmcnt-oldest)
    if(pc<8) OFF_GATHER_Q(q+1, vE);       // gathers in flight thru compute
    OFF_COMPUTE_Q2(w, cur);
    if(pc<8) OFF_VWRITE_Q(vE, cur^1);
    __syncthreads();
  }
  int p = px0 + wv*16 + lo;
#pragma unroll
  for(int mi=0;mi<2;mi++){
    int ob = mi*16 + hi*4;
    float4v a = (mi==0) ? acc[0] : acc[1];
#pragma unroll
    for(int r=0;r<4;r++){
      int o = ob + r;
      if(o < 27) om2[(size_t)((z*B_+b)*27+o)*HW + p] = a[r];
    }
  }
}

// ---------- DCN MFMA: Mb=256, Nb=64, FULL K (18 quads, BK=128) — R9 geometry ----------
// grid (64,4) = 256 blocks, 512 thr = 8 waves. W-first w[16], 1-deep gather.
// om read = sum of the two offset halves. Output: bf16 out1u[b][o][HW].
// Epilogue: per-o sum/sumsq from f32 accs -> atomicAdd st1raw (BN1 stats fused).
// b_dcn dropped: BN1 subtracts the per-channel mean, so a uniform bias cancels.
#define DCN_WLOAD_ALLQ(Q, W) do{ \
    _Pragma("unroll") \
    for(int c_=0;c_<4;c_++){ \
      const ushort* wp_ = Wdb + ((size_t)((Q)*4+c_)<<13) + wlane; \
      W[4*c_+0] = *(const short8*)(wp_); \
      W[4*c_+1] = *(const short8*)(wp_ + 512); \
      W[4*c_+2] = *(const short8*)(wp_ + 1024); \
      W[4*c_+3] = *(const short8*)(wp_ + 1536); \
    } \
  }while(0)

#define DCN_GATHER_Q(Q, C, CF) do{ \
    int k_ = (Q)>>1, c0_ = ((Q)&1)<<7; \
    int t_ = (k_<<6) + vpx; \
    int pk_ = sPk[t_]; CF = sCf[t_]; \
    int coff_ = c0_ + (vseg<<4); \
    int iy0_=pk_&63, iy1_=(pk_>>6)&63, ix0_=(pk_>>12)&63, ix1_=(pk_>>18)&63; \
    const ushort* p00_ = xtb + cbase + (((iy0_<<6)+ix0_)<<8) + coff_; \
    const ushort* p01_ = xtb + cbase + (((iy0_<<6)+ix1_)<<8) + coff_; \
    const ushort* p10_ = xtb + cbase + (((iy1_<<6)+ix0_)<<8) + coff_; \
    const ushort* p11_ = xtb + cbase + (((iy1_<<6)+ix1_)<<8) + coff_; \
    C[0] = *(const uint4*)(p00_);     C[4] = *(const uint4*)(p00_ + 8); \
    C[1] = *(const uint4*)(p01_);     C[5] = *(const uint4*)(p01_ + 8); \
    C[2] = *(const uint4*)(p10_);     C[6] = *(const uint4*)(p10_ + 8); \
    C[3] = *(const uint4*)(p11_);     C[7] = *(const uint4*)(p11_ + 8); \
  }while(0)

#define DCN_BLEND_H(C0,C1,C2,C3, CF, DST) do{ \
    union{ ushort us[8]; uint4 q; } rr_; \
    rr_.us[0] = f2bf(CF.x*bflo(C0.x)+CF.y*bflo(C1.x)+CF.z*bflo(C2.x)+CF.w*bflo(C3.x)); \
    rr_.us[1] = f2bf(CF.x*bfhi(C0.x)+CF.y*bfhi(C1.x)+CF.z*bfhi(C2.x)+CF.w*bfhi(C3.x)); \
    rr_.us[2] = f2bf(CF.x*bflo(C0.y)+CF.y*bflo(C1.y)+CF.z*bflo(C2.y)+CF.w*bflo(C3.y)); \
    rr_.us[3] = f2bf(CF.x*bfhi(C0.y)+CF.y*bfhi(C1.y)+CF.z*bfhi(C2.y)+CF.w*bfhi(C3.y)); \
    rr_.us[4] = f2bf(CF.x*bflo(C0.z)+CF.y*bflo(C1.z)+CF.z*bflo(C2.z)+CF.w*bflo(C3.z)); \
    rr_.us[5] = f2bf(CF.x*bfhi(C0.z)+CF.y*bfhi(C1.z)+CF.z*bfhi(C2.z)+CF.w*bfhi(C3.z)); \
    rr_.us[6] = f2bf(CF.x*bflo(C0.w)+CF.y*bflo(C1.w)+CF.z*bflo(C2.w)+CF.w*bflo(C3.w)); \
    rr_.us[7] = f2bf(CF.x*bfhi(C0.w)+CF.y*bfhi(C1.w)+CF.z*bfhi(C2.w)+CF.w*bfhi(C3.w)); \
    *(uint4*)(DST) = rr_.q; \
  }while(0)

#define DCN_BLEND_Q(C, CF, BUF) do{ \
    ushort* dp_ = &Vs[BUF][vpx*LSTR4 + (vseg<<4)]; \
    DCN_BLEND_H(C[0],C[1],C[2],C[3], CF, dp_); \
    DCN_BLEND_H(C[4],C[5],C[6],C[7], CF, dp_ + 8); \
  }while(0)

#define DCN_COMPUTE_Q2(W, BUF) do{ \
    const ushort* bp_ = &Vs[BUF][(pn0+lo)*LSTR4 + hi*8]; \
    _Pragma("unroll") \
    for(int c_=0;c_<4;c_++){ \
      short8 b0_ = *(const short8*)(bp_ + c_*32); \
      short8 b1_ = *(const short8*)(bp_ + c_*32 + 16*LSTR4); \
      acc[0][0] = __builtin_amdgcn_mfma_f32_16x16x32_bf16(W[4*c_+0], b0_, acc[0][0], 0,0,0); \
      acc[0][1] = __builtin_amdgcn_mfma_f32_16x16x32_bf16(W[4*c_+0], b1_, acc[0][1], 0,0,0); \
      acc[1][0] = __builtin_amdgcn_mfma_f32_16x16x32_bf16(W[4*c_+1], b0_, acc[1][0], 0,0,0); \
      acc[1][1] = __builtin_amdgcn_mfma_f32_16x16x32_bf16(W[4*c_+1], b1_, acc[1][1], 0,0,0); \
      acc[2][0] = __builtin_amdgcn_mfma_f32_16x16x32_bf16(W[4*c_+2], b0_, acc[2][0], 0,0,0); \
      acc[2][1] = __builtin_amdgcn_mfma_f32_16x16x32_bf16(W[4*c_+2], b1_, acc[2][1], 0,0,0); \
      acc[3][0] = __builtin_amdgcn_mfma_f32_16x16x32_bf16(W[4*c_+3], b0_, acc[3][0], 0,0,0); \
      acc[3][1] = __builtin_amdgcn_mfma_f32_16x16x32_bf16(W[4*c_+3], b1_, acc[3][1], 0,0,0); \
    } \
  }while(0)

__global__ __launch_bounds__(512) void k_dcn_mfma(const ushort* __restrict__ xtb,
                        const float* __restrict__ om2, const float* __restrict__ b_off,
                        const ushort* __restrict__ Wdb, ushort* __restrict__ out1u,
                        float* __restrict__ st1raw){
  __shared__ ushort Vs[2][64*LSTR4];   // 2 x 17408 B
  __shared__ int    sPk[576];
  __shared__ float4 sCf[576];
  int tid = threadIdx.x;
  int fb  = blockIdx.x + (blockIdx.y<<6);       // 0..255
  int b   = (fb&7)>>1;                          // XCD-b affinity
  int px0 = ((((fb>>3)<<1) | (fb&1))) << 6;

  for(int t=tid; t<576; t+=512){
    int k = t>>6, px = t&63;
    int p = px0 + px, hh = p>>6, ww = p&63;
    const float* oma = om2 + (size_t)b*27*HW + p;
    const float* omb = oma + (size_t)B_*27*HW;
    float dy = oma[(size_t)k*HW]      + omb[(size_t)k*HW]      + b_off[k];
    float dx = oma[(size_t)(9+k)*HW]  + omb[(size_t)(9+k)*HW]  + b_off[9+k];
    float mo = sigmoidf_(oma[(size_t)(18+k)*HW] + omb[(size_t)(18+k)*HW] + b_off[18+k]);
    float py  = dy + (float)(hh + k/3 - 1);
    float pxf = dx + (float)(ww + k%3 - 1);
    float y0 = floorf(py), x0 = floorf(pxf);
    float wy = py - y0, wx = pxf - x0;
    float y1 = y0 + 1.0f, x1 = x0 + 1.0f;
    bool vy0 = (y0>=0.f)&&(y0<=63.f), vy1 = (y1>=0.f)&&(y1<=63.f);
    bool vx0 = (x0>=0.f)&&(x0<=63.f), vx1 = (x1>=0.f)&&(x1<=63.f);
    int iy0 = (int)fminf(fmaxf(y0,0.f),63.f);
    int iy1 = (int)fminf(fmaxf(y1,0.f),63.f);
    int ix0 = (int)fminf(fmaxf(x0,0.f),63.f);
    int ix1 = (int)fminf(fmaxf(x1,0.f),63.f);
    sPk[t] = iy0 | (iy1<<6) | (ix0<<12) | (ix1<<18);
    sCf[t] = make_float4((vy0&&vx0)? (1.f-wy)*(1.f-wx)*mo : 0.f,
                         (vy0&&vx1)? (1.f-wy)*wx*mo       : 0.f,
                         (vy1&&vx0)? wy*(1.f-wx)*mo       : 0.f,
                         (vy1&&vx1)? wy*wx*mo             : 0.f);
  }
  __syncthreads();

  int lane = tid&63, wv = tid>>6, lo = lane&15, hi = lane>>4;
  int om0 = (wv>>1)*64, pn0 = (wv&1)*32;
  float4v acc[4][2];
#pragma unroll
  for(int i=0;i<4;i++)
#pragma unroll
    for(int j=0;j<2;j++) acc[i][j] = (float4v){0.f,0.f,0.f,0.f};
  int cbase = (b*HW)<<8;
  int vpx = tid>>3, vseg = tid&7;               // 64 px x 8 thr, 16 ch each
  const int wlane = (om0+lo)*32 + hi*8;

  short8 w[16];
  uint4 cE[8];
  float4 fE;

  // ---- prologue: gather+blend quad 0 -> Vs[0] ----
  DCN_GATHER_Q(0, cE, fE);
  DCN_BLEND_Q(cE, fE, 0);
  __syncthreads();

#pragma unroll 1
  for(int pc=0; pc<18; ++pc){
    int cur = pc&1;
    DCN_WLOAD_ALLQ(pc, w);                  // W FIRST (vmcnt-oldest)
    if(pc<17) DCN_GATHER_Q(pc+1, cE, fE);   // gathers in flight thru compute
    DCN_COMPUTE_Q2(w, cur);                 // waits only W
    if(pc<17) DCN_BLEND_Q(cE, fE, cur^1);   // waits gathers (covered)
    __syncthreads();
  }

  // epilogue: bf16 store + fused BN1 stats (per-o sum/sumsq over this wave's 32 px)
  ushort* op0 = out1u + ((size_t)(b*COUT)<<12) + px0 + pn0 + lo;
#pragma unroll
  for(int i=0;i<4;i++){
    int ob = om0 + i*16 + hi*4;
#pragma unroll
    for(int r=0;r<4;r++){
      int o = ob + r;
      ushort* op = op0 + ((size_t)o<<12);
      float v0 = acc[i][0][r], v1 = acc[i][1][r];
      op[0]  = f2bf(v0);
      op[16] = f2bf(v1);
      float s  = v0 + v1;
      float q2 = v0*v0 + v1*v1;
#pragma unroll
      for(int st=1; st<16; st<<=1){ s += __shfl_xor(s, st); q2 += __shfl_xor(q2, st); }
      if(lo == 0){
        atomicAdd(&st1raw[2*o],   s);
        atomicAdd(&st1raw[2*o+1], q2);
      }
    }
  }
}

// ---------- BN1 apply + relu + transpose -> y1b bf16 [b][p][c] (stats from raw sums) ----------
__global__ void k_bn1_apply_t(const ushort* __restrict__ out1u, const float* __restrict__ st1raw,
                              const float* __restrict__ gamma, const float* __restrict__ beta,
                              ushort* __restrict__ y1b){
  __shared__ float ts[32][33];
  int tx = threadIdx.x & 31, ty = threadIdx.x >> 5;
  int p0 = blockIdx.x*32, o0 = blockIdx.y*32, b = blockIdx.z;
  const float inv_n = 1.f/16384.f;   // B_*HW
#pragma unroll
  for(int q=0;q<4;q++){
    int oo = ty + q*8; int o = o0 + oo;
    float mean = st1raw[2*o] * inv_n;
    float var  = st1raw[2*o+1] * inv_n - mean*mean;
    float rstd = rsqrtf(var + 1e-5f);
    float scale = rstd * gamma[o];
    float shift = beta[o] - mean * scale;
    float v = bflo((unsigned)out1u[((size_t)(b*COUT+o)<<12) + p0+tx]);
    ts[oo][tx] = fmaxf(v*scale + shift, 0.f);
  }
  __syncthreads();
#pragma unroll
  for(int q=0;q<4;q++){
    int pr = ty + q*8;
    y1b[((size_t)(b*HW + p0+pr)<<8) + o0+tx] = f2bf(ts[tx][pr]);
  }
}

// ---------- conv-transpose MFMA v3: Mb=256 o, Nb=256 px, one (b,pp) ----------
// grid (16,4,4), 512 thr = 8 waves (2/SIMD). XCD-b affinity remap.
// Epilogue: bf16 store + fused BN2 stats (per-o sum/sumsq from f32 accs).
__global__ __launch_bounds__(512) void k_convt_mfma(const ushort* __restrict__ y1b,
                        const ushort* __restrict__ WT2c,
                        ushort* __restrict__ ct, float* __restrict__ st2raw){
  __shared__ ushort Vs[2][256*LSTR2];   // 2 x 36864 B
  __shared__ int sIdx[1024];
  int tid = threadIdx.x;
  int fb  = blockIdx.x + (blockIdx.y<<4) + (blockIdx.z<<6);  // 0..255
  int jj = fb&7, rr2 = fb>>3;
  int b   = jj>>1;
  int pp  = ((rr2>>4)<<1) | (jj&1);
  int px0 = (rr2&15) << 8;
  int ph = pp>>1, pw = pp&1;

  for(int t=tid; t<1024; t+=512){
    int ab = t>>8, px = t&255;
    int a = ab>>1, bb = ab&1;
    int p = px0+px, r = p>>6, s = p&63;
    int ih = r + ph - 1 + a, iw = s + pw - 1 + bb;
    sIdx[t] = (ih>=0 && ih<64 && iw>=0 && iw<64) ? ((b*HW + ih*64+iw)<<8) : -1;
  }
  __syncthreads();

  int lane = tid&63, wv = tid>>6, lo = lane&15, hi = lane>>4;
  int om0 = (wv>>1)*64;
  int pn0 = (wv&1)*128;
  float4v acc[4][8];
#pragma unroll
  for(int i=0;i<4;i++)
#pragma unroll
    for(int j=0;j<8;j++) acc[i][j] = (float4v){0.f,0.f,0.f,0.f};

  const ushort* wbase = WT2c + ((size_t)pp<<18);
  const int wlaneb = (om0+lo)*32 + hi*8;
  int vpx = tid>>1, vseg = tid&1;
  uint4 vpre[4];

#define CT3_PREFETCH(PC) do{ \
    int kc0_ = (PC)*2; \
    int ab_ = kc0_>>3, c0_ = (kc0_&7)<<5; \
    int idx_ = sIdx[(ab_<<8) + vpx]; \
    int co_ = c0_ + vseg*32; \
    vpre[0]=make_uint4(0,0,0,0); vpre[1]=make_uint4(0,0,0,0); \
    vpre[2]=make_uint4(0,0,0,0); vpre[3]=make_uint4(0,0,0,0); \
    if(idx_ >= 0){ \
      vpre[0] = *(const uint4*)(y1b + idx_ + co_); \
      vpre[1] = *(const uint4*)(y1b + idx_ + co_ + 8); \
      vpre[2] = *(const uint4*)(y1b + idx_ + co_ + 16); \
      vpre[3] = *(const uint4*)(y1b + idx_ + co_ + 24); \
    } \
  }while(0)

#define CT3_WRITE(BUF) do{ \
    ushort* vp_ = &Vs[BUF][vpx*LSTR2 + vseg*32]; \
    *(uint4*)(vp_)      = vpre[0]; \
    *(uint4*)(vp_ + 8)  = vpre[1]; \
    *(uint4*)(vp_ + 16) = vpre[2]; \
    *(uint4*)(vp_ + 24) = vpre[3]; \
  }while(0)

  CT3_PREFETCH(0);
  CT3_WRITE(0);
  __syncthreads();

#pragma unroll 1
  for(int pc=0; pc<16; ++pc){
    int cur = pc&1;
    if(pc < 15) CT3_PREFETCH(pc+1);
#pragma unroll
    for(int c=0; c<2; ++c){
      const ushort* wp = wbase + ((size_t)(((pc<<1)|c))<<13) + wlaneb;
      const ushort* bp = &Vs[cur][(pn0+lo)*LSTR2 + c*32 + hi*8];
      short8 bfr[8];
#pragma unroll
      for(int j=0;j<8;j++) bfr[j] = *(const short8*)(bp + j*16*LSTR2);
#pragma unroll
      for(int i=0;i<4;i++){
        short8 afr = *(const short8*)(wp + i*512);
#pragma unroll
        for(int j=0;j<8;j++)
          acc[i][j] = __builtin_amdgcn_mfma_f32_16x16x32_bf16(afr, bfr[j], acc[i][j], 0,0,0);
      }
    }
    if(pc < 15) CT3_WRITE(cur^1);
    __syncthreads();
  }

  // epilogue: bf16 store + fused BN2 stats
  ushort* cb = ct + (((size_t)(pp*4 + b)*256)<<12);
#pragma unroll
  for(int i=0;i<4;i++){
#pragma unroll
    for(int r=0;r<4;r++){
      int o = om0 + i*16 + hi*4 + r;
      ushort* row = cb + ((size_t)o<<12) + px0 + pn0 + lo;
      float s = 0.f, q2 = 0.f;
#pragma unroll
      for(int j=0;j<8;j++){
        float v = acc[i][j][r];
        row[j*16] = f2bf(v);
        s += v; q2 += v*v;
      }
#pragma unroll
      for(int st=1; st<16; st<<=1){ s += __shfl_xor(s, st); q2 += __shfl_xor(q2, st); }
      if(lo == 0){
        atomicAdd(&st2raw[2*o],   s);
        atomicAdd(&st2raw[2*o+1], q2);
      }
    }
  }
}

// ---------- BN2 apply + relu + parity interleave: ct bf16 -> out f32 (stats from raw) ----------
__global__ void k_bn2_apply(const ushort* __restrict__ ct, const float* __restrict__ st2raw,
                            const float* __restrict__ gamma, const float* __restrict__ beta,
                            float* __restrict__ out){
  int gid = blockIdx.x*256 + threadIdx.x;   // grid 16384
  int e4 = gid<<2;
  int b = e4>>22, o = (e4>>14)&255, q = e4&16383;
  int H2 = q>>7, W2 = q&127;
  int r = H2>>1, ph = H2&1, s0 = W2>>1;
  size_t base0 = (((size_t)((ph*2)*4 + b)*256 + o)<<12) + r*64 + s0;
  unsigned u0 = *(const unsigned*)(ct + base0);
  unsigned u1 = *(const unsigned*)(ct + base0 + ((size_t)4<<20));
  const float inv_n = 1.f/65536.f;   // 16*4096
  float mean = st2raw[2*o] * inv_n;
  float rstd = rsqrtf(st2raw[2*o+1]*inv_n - mean*mean + 1e-5f);
  float sc = rstd * gamma[o];
  float sh = beta[o] - mean * sc;
  float4 v;
  v.x = fmaxf(bflo(u0)*sc + sh, 0.f);
  v.y = fmaxf(bflo(u1)*sc + sh, 0.f);
  v.z = fmaxf(bfhi(u0)*sc + sh, 0.f);
  v.w = fmaxf(bfhi(u1)*sc + sh, 0.f);
  *(float4*)(out + e4) = v;
}

extern "C" void kernel_launch(void* const* d_in, const int* in_sizes, int n_in,
                              void* d_out, int out_size, void* d_ws, size_t ws_size,
                              hipStream_t stream){
  (void)in_sizes; (void)n_in; (void)out_size; (void)ws_size;
  const float* x     = (const float*)d_in[0];
  const float* w_off = (const float*)d_in[1];
  const float* b_off = (const float*)d_in[2];
  const float* w_dcn = (const float*)d_in[3];
  const float* gamma1= (const float*)d_in[5];
  const float* beta1 = (const float*)d_in[6];
  const float* w_up  = (const float*)d_in[7];
  const float* gamma2= (const float*)d_in[8];
  const float* beta2 = (const float*)d_in[9];
  float* out = (float*)d_out;

  // Workspace (floats). ct (bf16, 32 MB = 8388608 floats) aliases om2+xtb+out1u,
  // all of which are dead before k_convt_mfma runs.
  float* ws    = (float*)d_ws;
  ushort* ct   = (ushort*)ws;                      // [0, 8388608) floats
  float* om2   = ws;                               // 2x442368 = 884736 floats
  ushort* xtb  = (ushort*)(ws + 884736);           // 4194304 bf16 = 2097152 floats
  ushort* out1u= (ushort*)(ws + 884736 + 2097152); // 4194304 bf16 = 2097152 floats
                                                   // ends 884736+2097152+2097152 = 5079040 <= 8388608
  float* base2 = ws + 8388608;
  ushort* y1b  = (ushort*)base2;                                   // 4194304 bf16
  ushort* WT2c = (ushort*)(base2 + 2097152);                       // 1048576 bf16
  ushort* Wdb  = (ushort*)(base2 + 2097152 + 524288);              // 589824 bf16
  ushort* Wob  = (ushort*)(base2 + 2097152 + 524288 + 294912);     // 73728 bf16
  float* st1raw= base2 + 2097152 + 524288 + 294912 + 36864;        // 512
  float* st2raw= st1raw + 512;                                     // 512

  k_transpose_x <<<dim3(128,8,4), 256, 0, stream>>>(x, xtb);
  k_build_all   <<<6688, 256, 0, stream>>>(w_off, w_dcn, w_up, Wob, Wdb, WT2c, st1raw, st2raw);
  k_offset_mfma <<<dim3(64,4,2), 256, 0, stream>>>(xtb, Wob, om2);
  k_dcn_mfma    <<<dim3(64,4),   512, 0, stream>>>(xtb, om2, b_off, Wdb, out1u, st1raw);
  k_bn1_apply_t <<<dim3(128,8,4), 256, 0, stream>>>(out1u, st1raw, gamma1, beta1, y1b);
  k_convt_mfma  <<<dim3(16,4,4),  512, 0, stream>>>(y1b, WT2c, ct, st2raw);
  k_bn2_apply   <<<16384,256, 0, stream>>>(ct, st2raw, gamma2, beta2, out);
}

// Round 15
// 254.573 us; speedup vs baseline: 2.0390x; 2.0390x over previous
//
#include <hip/hip_runtime.h>
#include <hip/hip_bf16.h>
#include <math.h>

// Problem constants
#define B_   4
#define CIN  256
#define COUT 256
#define HW   4096   // 64*64

typedef __attribute__((ext_vector_type(8))) short short8;
typedef __attribute__((ext_vector_type(4))) float float4v;

// LDS row strides (ushorts).
// LSTR2 (64-ch rows): 144 B = 36 dwords (36 mod 32 = 4 -> proven 2-way pattern).
// LSTR4 (128-ch rows): 272 B = 68 dwords (68 mod 32 = 4 -> same pattern).
#define LSTR  40
#define LSTR2 72
#define LSTR4 136

__device__ __forceinline__ float sigmoidf_(float v){ return 1.0f/(1.0f+expf(-v)); }
__device__ __forceinline__ ushort f2bf(float f){
  union { float f; unsigned u; } x; x.f = f;
  unsigned r = x.u + 0x7fffu + ((x.u>>16)&1u);
  return (ushort)(r>>16);
}
__device__ __forceinline__ float bflo(unsigned u){ union{unsigned u; float f;} c; c.u = u<<16;          return c.f; }
__device__ __forceinline__ float bfhi(unsigned u){ union{unsigned u; float f;} c; c.u = u & 0xffff0000u; return c.f; }

// ---------- transpose x [B][C][HW] -> xtb [B][HW][C] bf16 ----------
__global__ void k_transpose_x(const float* __restrict__ x, ushort* __restrict__ xtb){
  __shared__ float ts[32][33];
  int tx = threadIdx.x & 31, ty = threadIdx.x >> 5;
  int p0 = blockIdx.x * 32, c0 = blockIdx.y * 32, b = blockIdx.z;
  const float* xb = x + (size_t)b*CIN*HW;
#pragma unroll
  for(int q=0;q<4;q++){
    int c = ty + q*8;
    ts[c][tx] = xb[(size_t)(c0+c)*HW + p0+tx];
  }
  __syncthreads();
#pragma unroll
  for(int q=0;q<4;q++){
    int pr = ty + q*8;
    xtb[((size_t)(b*HW + p0+pr)<<8) + c0+tx] = f2bf(ts[tx][pr]);
  }
}

// ---------- fused weight re-layouts (bf16, K-chunked [kc][o][kk]) ----------
__global__ void k_build_all(const float* __restrict__ w_off, const float* __restrict__ w_dcn,
                            const float* __restrict__ w_up,
                            ushort* __restrict__ Wob, ushort* __restrict__ Wdb,
                            ushort* __restrict__ WT2c){
  int bid = blockIdx.x;
  if(bid < 288){
    int f = bid*256 + threadIdx.x;
    int kc = f>>10, o = (f>>5)&31, kk = f&31;
    int k = kc*32 + kk, tap = k>>8, c = k&255;
    float v = (o < 27) ? w_off[(size_t)o*2304 + c*9 + tap] : 0.f;
    Wob[f] = f2bf(v);
  } else if(bid < 288+2304){
    int f = (bid-288)*256 + threadIdx.x;
    int kc = f>>13, o = (f>>5)&255, kk = f&31;
    int k = kc>>3, c = ((kc&7)<<5) | kk;
    Wdb[f] = f2bf(w_dcn[(size_t)o*2304 + c*9 + k]);
  } else {
    int f = (bid-2592)*256 + threadIdx.x;
    int pp = f>>18, kc = (f>>13)&31, o = (f>>5)&255, kk = f&31;
    int k = kc*32 + kk, ab = k>>8, c = k&255;
    int a = ab>>1, bb = ab&1, ph = pp>>1, pw = pp&1;
    WT2c[f] = f2bf(w_up[(size_t)(c*COUT+o)*16 + (3-ph-2*a)*4 + (3-pw-2*bb)]);
  }
}

// ---------- offset conv MFMA: M=32(27), Nb=64 px, K-SPLIT (z-half does 9 quads) ----------
// grid (64,4,2) = 512 blocks (R13-proven). 256 thr = 4 waves, quad chunks,
// W-first JIT, 1-deep gather. Output: f32 partial om2[z][b][27][HW].
__global__ __launch_bounds__(256) void k_offset_mfma(const ushort* __restrict__ xtb,
                        const ushort* __restrict__ Wob, float* __restrict__ om2){
  __shared__ ushort Vs[2][64*LSTR4];   // 2 x 17408 B
  __shared__ int sIdx[576];
  int tid = threadIdx.x;
  int fb  = blockIdx.x + (blockIdx.y<<6);       // 0..255
  int b   = (fb&7)>>1;                          // XCD-b affinity
  int px0 = ((((fb>>3)<<1) | (fb&1))) << 6;
  int z   = blockIdx.z;                         // K-half
  for(int t=tid; t<576; t+=256){
    int tap = t>>6, px = t&63;
    int p = px0+px, hh = p>>6, ww = p&63;
    int ih = hh + tap/3 - 1, iw = ww + tap%3 - 1;
    sIdx[t] = (ih>=0 && ih<64 && iw>=0 && iw<64) ? ((b*HW + ih*64+iw)<<8) : -1;
  }
  __syncthreads();

  int lane = tid&63, wv = tid>>6, lo = lane&15, hi = lane>>4;
  float4v acc[2];
  acc[0] = acc[1] = (float4v){0.f,0.f,0.f,0.f};
  int vpx = tid>>2, vseg = tid&3;               // 64 px x 4 thr, 32 ch each
  const int wlane = lo*32 + hi*8;

#define OFF_WLOAD_ALLQ(Q, W) do{ \
    _Pragma("unroll") \
    for(int c_=0;c_<4;c_++){ \
      const ushort* wp_ = Wob + (((Q)*4+c_)<<10) + wlane; \
      W[2*c_+0] = *(const short8*)(wp_); \
      W[2*c_+1] = *(const short8*)(wp_ + 512); \
    } \
  }while(0)

#define OFF_GATHER_Q(Q, V) do{ \
    int k_ = (Q)>>1, c0_ = ((Q)&1)<<7; \
    int idx_ = sIdx[(k_<<6)+vpx]; \
    int coff_ = c0_ + (vseg<<5); \
    V[0]=make_uint4(0,0,0,0); V[1]=make_uint4(0,0,0,0); \
    V[2]=make_uint4(0,0,0,0); V[3]=make_uint4(0,0,0,0); \
    if(idx_ >= 0){ \
      V[0] = *(const uint4*)(xtb + idx_ + coff_); \
      V[1] = *(const uint4*)(xtb + idx_ + coff_ + 8); \
      V[2] = *(const uint4*)(xtb + idx_ + coff_ + 16); \
      V[3] = *(const uint4*)(xtb + idx_ + coff_ + 24); \
    } \
  }while(0)

#define OFF_VWRITE_Q(V, BUF) do{ \
    ushort* vp_ = &Vs[BUF][vpx*LSTR4 + (vseg<<5)]; \
    *(uint4*)(vp_)      = V[0]; \
    *(uint4*)(vp_ + 8)  = V[1]; \
    *(uint4*)(vp_ + 16) = V[2]; \
    *(uint4*)(vp_ + 24) = V[3]; \
  }while(0)

#define OFF_COMPUTE_Q2(W, BUF) do{ \
    const ushort* bp_ = &Vs[BUF][(wv*16+lo)*LSTR4 + hi*8]; \
    _Pragma("unroll") \
    for(int c_=0;c_<4;c_++){ \
      short8 ba_ = *(const short8*)(bp_ + c_*32); \
      acc[0] = __builtin_amdgcn_mfma_f32_16x16x32_bf16(W[2*c_+0], ba_, acc[0], 0,0,0); \
      acc[1] = __builtin_amdgcn_mfma_f32_16x16x32_bf16(W[2*c_+1], ba_, acc[1], 0,0,0); \
    } \
  }while(0)

  short8 w[8];
  uint4 vE[4];
  // ---- prologue: gather quad z*9 -> Vs[0] ----
  OFF_GATHER_Q(z*9, vE);
  OFF_VWRITE_Q(vE, 0);
  __syncthreads();

#pragma unroll 1
  for(int pc=0; pc<9; ++pc){
    int cur = pc&1;
    int q = z*9 + pc;
    OFF_WLOAD_ALLQ(q, w);                 // W first (vmcnt-oldest)
    if(pc<8) OFF_GATHER_Q(q+1, vE);       // gathers in flight thru compute
    OFF_COMPUTE_Q2(w, cur);
    if(pc<8) OFF_VWRITE_Q(vE, cur^1);
    __syncthreads();
  }
  int p = px0 + wv*16 + lo;
#pragma unroll
  for(int mi=0;mi<2;mi++){
    int ob = mi*16 + hi*4;
    float4v a = (mi==0) ? acc[0] : acc[1];
#pragma unroll
    for(int r=0;r<4;r++){
      int o = ob + r;
      if(o < 27) om2[(size_t)((z*B_+b)*27+o)*HW + p] = a[r];
    }
  }
}

// ---------- DCN MFMA: Mb=256, Nb=64, FULL K (18 quads, BK=128) — R9 geometry ----------
// grid (64,4) = 256 blocks, 512 thr = 8 waves. W-first w[16], 1-deep gather.
// om read = sum of the two offset halves. Output: bf16 out1u[b][o][HW] (single buffer).
// b_dcn dropped: BN1 subtracts the per-channel mean, so a uniform bias cancels.
#define DCN_WLOAD_ALLQ(Q, W) do{ \
    _Pragma("unroll") \
    for(int c_=0;c_<4;c_++){ \
      const ushort* wp_ = Wdb + ((size_t)((Q)*4+c_)<<13) + wlane; \
      W[4*c_+0] = *(const short8*)(wp_); \
      W[4*c_+1] = *(const short8*)(wp_ + 512); \
      W[4*c_+2] = *(const short8*)(wp_ + 1024); \
      W[4*c_+3] = *(const short8*)(wp_ + 1536); \
    } \
  }while(0)

#define DCN_GATHER_Q(Q, C, CF) do{ \
    int k_ = (Q)>>1, c0_ = ((Q)&1)<<7; \
    int t_ = (k_<<6) + vpx; \
    int pk_ = sPk[t_]; CF = sCf[t_]; \
    int coff_ = c0_ + (vseg<<4); \
    int iy0_=pk_&63, iy1_=(pk_>>6)&63, ix0_=(pk_>>12)&63, ix1_=(pk_>>18)&63; \
    const ushort* p00_ = xtb + cbase + (((iy0_<<6)+ix0_)<<8) + coff_; \
    const ushort* p01_ = xtb + cbase + (((iy0_<<6)+ix1_)<<8) + coff_; \
    const ushort* p10_ = xtb + cbase + (((iy1_<<6)+ix0_)<<8) + coff_; \
    const ushort* p11_ = xtb + cbase + (((iy1_<<6)+ix1_)<<8) + coff_; \
    C[0] = *(const uint4*)(p00_);     C[4] = *(const uint4*)(p00_ + 8); \
    C[1] = *(const uint4*)(p01_);     C[5] = *(const uint4*)(p01_ + 8); \
    C[2] = *(const uint4*)(p10_);     C[6] = *(const uint4*)(p10_ + 8); \
    C[3] = *(const uint4*)(p11_);     C[7] = *(const uint4*)(p11_ + 8); \
  }while(0)

#define DCN_BLEND_H(C0,C1,C2,C3, CF, DST) do{ \
    union{ ushort us[8]; uint4 q; } rr_; \
    rr_.us[0] = f2bf(CF.x*bflo(C0.x)+CF.y*bflo(C1.x)+CF.z*bflo(C2.x)+CF.w*bflo(C3.x)); \
    rr_.us[1] = f2bf(CF.x*bfhi(C0.x)+CF.y*bfhi(C1.x)+CF.z*bfhi(C2.x)+CF.w*bfhi(C3.x)); \
    rr_.us[2] = f2bf(CF.x*bflo(C0.y)+CF.y*bflo(C1.y)+CF.z*bflo(C2.y)+CF.w*bflo(C3.y)); \
    rr_.us[3] = f2bf(CF.x*bfhi(C0.y)+CF.y*bfhi(C1.y)+CF.z*bfhi(C2.y)+CF.w*bfhi(C3.y)); \
    rr_.us[4] = f2bf(CF.x*bflo(C0.z)+CF.y*bflo(C1.z)+CF.z*bflo(C2.z)+CF.w*bflo(C3.z)); \
    rr_.us[5] = f2bf(CF.x*bfhi(C0.z)+CF.y*bfhi(C1.z)+CF.z*bfhi(C2.z)+CF.w*bfhi(C3.z)); \
    rr_.us[6] = f2bf(CF.x*bflo(C0.w)+CF.y*bflo(C1.w)+CF.z*bflo(C2.w)+CF.w*bflo(C3.w)); \
    rr_.us[7] = f2bf(CF.x*bfhi(C0.w)+CF.y*bfhi(C1.w)+CF.z*bfhi(C2.w)+CF.w*bfhi(C3.w)); \
    *(uint4*)(DST) = rr_.q; \
  }while(0)

#define DCN_BLEND_Q(C, CF, BUF) do{ \
    ushort* dp_ = &Vs[BUF][vpx*LSTR4 + (vseg<<4)]; \
    DCN_BLEND_H(C[0],C[1],C[2],C[3], CF, dp_); \
    DCN_BLEND_H(C[4],C[5],C[6],C[7], CF, dp_ + 8); \
  }while(0)

#define DCN_COMPUTE_Q2(W, BUF) do{ \
    const ushort* bp_ = &Vs[BUF][(pn0+lo)*LSTR4 + hi*8]; \
    _Pragma("unroll") \
    for(int c_=0;c_<4;c_++){ \
      short8 b0_ = *(const short8*)(bp_ + c_*32); \
      short8 b1_ = *(const short8*)(bp_ + c_*32 + 16*LSTR4); \
      acc[0][0] = __builtin_amdgcn_mfma_f32_16x16x32_bf16(W[4*c_+0], b0_, acc[0][0], 0,0,0); \
      acc[0][1] = __builtin_amdgcn_mfma_f32_16x16x32_bf16(W[4*c_+0], b1_, acc[0][1], 0,0,0); \
      acc[1][0] = __builtin_amdgcn_mfma_f32_16x16x32_bf16(W[4*c_+1], b0_, acc[1][0], 0,0,0); \
      acc[1][1] = __builtin_amdgcn_mfma_f32_16x16x32_bf16(W[4*c_+1], b1_, acc[1][1], 0,0,0); \
      acc[2][0] = __builtin_amdgcn_mfma_f32_16x16x32_bf16(W[4*c_+2], b0_, acc[2][0], 0,0,0); \
      acc[2][1] = __builtin_amdgcn_mfma_f32_16x16x32_bf16(W[4*c_+2], b1_, acc[2][1], 0,0,0); \
      acc[3][0] = __builtin_amdgcn_mfma_f32_16x16x32_bf16(W[4*c_+3], b0_, acc[3][0], 0,0,0); \
      acc[3][1] = __builtin_amdgcn_mfma_f32_16x16x32_bf16(W[4*c_+3], b1_, acc[3][1], 0,0,0); \
    } \
  }while(0)

__global__ __launch_bounds__(512) void k_dcn_mfma(const ushort* __restrict__ xtb,
                        const float* __restrict__ om2, const float* __restrict__ b_off,
                        const ushort* __restrict__ Wdb, ushort* __restrict__ out1u){
  __shared__ ushort Vs[2][64*LSTR4];   // 2 x 17408 B
  __shared__ int    sPk[576];
  __shared__ float4 sCf[576];
  int tid = threadIdx.x;
  int fb  = blockIdx.x + (blockIdx.y<<6);       // 0..255
  int b   = (fb&7)>>1;                          // XCD-b affinity
  int px0 = ((((fb>>3)<<1) | (fb&1))) << 6;

  for(int t=tid; t<576; t+=512){
    int k = t>>6, px = t&63;
    int p = px0 + px, hh = p>>6, ww = p&63;
    const float* oma = om2 + (size_t)b*27*HW + p;
    const float* omb = oma + (size_t)B_*27*HW;
    float dy = oma[(size_t)k*HW]      + omb[(size_t)k*HW]      + b_off[k];
    float dx = oma[(size_t)(9+k)*HW]  + omb[(size_t)(9+k)*HW]  + b_off[9+k];
    float mo = sigmoidf_(oma[(size_t)(18+k)*HW] + omb[(size_t)(18+k)*HW] + b_off[18+k]);
    float py  = dy + (float)(hh + k/3 - 1);
    float pxf = dx + (float)(ww + k%3 - 1);
    float y0 = floorf(py), x0 = floorf(pxf);
    float wy = py - y0, wx = pxf - x0;
    float y1 = y0 + 1.0f, x1 = x0 + 1.0f;
    bool vy0 = (y0>=0.f)&&(y0<=63.f), vy1 = (y1>=0.f)&&(y1<=63.f);
    bool vx0 = (x0>=0.f)&&(x0<=63.f), vx1 = (x1>=0.f)&&(x1<=63.f);
    int iy0 = (int)fminf(fmaxf(y0,0.f),63.f);
    int iy1 = (int)fminf(fmaxf(y1,0.f),63.f);
    int ix0 = (int)fminf(fmaxf(x0,0.f),63.f);
    int ix1 = (int)fminf(fmaxf(x1,0.f),63.f);
    sPk[t] = iy0 | (iy1<<6) | (ix0<<12) | (ix1<<18);
    sCf[t] = make_float4((vy0&&vx0)? (1.f-wy)*(1.f-wx)*mo : 0.f,
                         (vy0&&vx1)? (1.f-wy)*wx*mo       : 0.f,
                         (vy1&&vx0)? wy*(1.f-wx)*mo       : 0.f,
                         (vy1&&vx1)? wy*wx*mo             : 0.f);
  }
  __syncthreads();

  int lane = tid&63, wv = tid>>6, lo = lane&15, hi = lane>>4;
  int om0 = (wv>>1)*64, pn0 = (wv&1)*32;
  float4v acc[4][2];
#pragma unroll
  for(int i=0;i<4;i++)
#pragma unroll
    for(int j=0;j<2;j++) acc[i][j] = (float4v){0.f,0.f,0.f,0.f};
  int cbase = (b*HW)<<8;
  int vpx = tid>>3, vseg = tid&7;               // 64 px x 8 thr, 16 ch each
  const int wlane = (om0+lo)*32 + hi*8;

  short8 w[16];
  uint4 cE[8];
  float4 fE;

  // ---- prologue: gather+blend quad 0 -> Vs[0] ----
  DCN_GATHER_Q(0, cE, fE);
  DCN_BLEND_Q(cE, fE, 0);
  __syncthreads();

#pragma unroll 1
  for(int pc=0; pc<18; ++pc){
    int cur = pc&1;
    DCN_WLOAD_ALLQ(pc, w);                  // W FIRST (vmcnt-oldest)
    if(pc<17) DCN_GATHER_Q(pc+1, cE, fE);   // gathers in flight thru compute
    DCN_COMPUTE_Q2(w, cur);                 // waits only W
    if(pc<17) DCN_BLEND_Q(cE, fE, cur^1);   // waits gathers (covered)
    __syncthreads();
  }

  // epilogue: bf16 store (no fused stats — R14 showed contended atomics cost 145us)
  ushort* op0 = out1u + ((size_t)(b*COUT)<<12) + px0 + pn0 + lo;
#pragma unroll
  for(int i=0;i<4;i++){
    int ob = om0 + i*16 + hi*4;
#pragma unroll
    for(int r=0;r<4;r++){
      int o = ob + r;
      ushort* op = op0 + ((size_t)o<<12);
      op[0]  = f2bf(acc[i][0][r]);
      op[16] = f2bf(acc[i][1][r]);
    }
  }
}

// ---------- batchnorm stats over single bf16 out1 [b][o][4096] ----------
__global__ void k_bn_stats_bf1(const ushort* __restrict__ out1u, float* __restrict__ stats){
  int o = blockIdx.x, tid = threadIdx.x;
  float s=0.f, ss=0.f;
  for(int b=0;b<B_;b++){
    const ushort* p = out1u + ((size_t)(b*COUT+o)<<12);
    for(int i=tid*8; i<4096; i+=2048){
      uint4 v = *(const uint4*)(p + i);
      float f;
      f=bflo(v.x); s+=f; ss+=f*f;  f=bfhi(v.x); s+=f; ss+=f*f;
      f=bflo(v.y); s+=f; ss+=f*f;  f=bfhi(v.y); s+=f; ss+=f*f;
      f=bflo(v.z); s+=f; ss+=f*f;  f=bfhi(v.z); s+=f; ss+=f*f;
      f=bflo(v.w); s+=f; ss+=f*f;  f=bfhi(v.w); s+=f; ss+=f*f;
    }
  }
  __shared__ float rs[256], rss[256];
  rs[tid]=s; rss[tid]=ss; __syncthreads();
  for(int st=128; st>0; st>>=1){
    if(tid<st){ rs[tid]+=rs[tid+st]; rss[tid]+=rss[tid+st]; }
    __syncthreads();
  }
  if(tid==0){
    float n = (float)(B_*HW);
    float mean = rs[0]/n;
    float var  = rss[0]/n - mean*mean;
    stats[o*2] = mean; stats[o*2+1] = rsqrtf(var + 1e-5f);
  }
}

// ---------- batchnorm stats over bf16 ct [16 planes][o][4096] ----------
__global__ void k_bn_stats_ct(const ushort* __restrict__ ct, float* __restrict__ stats){
  int o = blockIdx.x, tid = threadIdx.x;
  float s=0.f, ss=0.f;
  for(int pl=0; pl<16; ++pl){
    const ushort* p = ct + (((size_t)(pl*256 + o))<<12);
    for(int i=tid*8; i<4096; i+=2048){
      uint4 v = *(const uint4*)(p + i);
      float f;
      f=bflo(v.x); s+=f; ss+=f*f;  f=bfhi(v.x); s+=f; ss+=f*f;
      f=bflo(v.y); s+=f; ss+=f*f;  f=bfhi(v.y); s+=f; ss+=f*f;
      f=bflo(v.z); s+=f; ss+=f*f;  f=bfhi(v.z); s+=f; ss+=f*f;
      f=bflo(v.w); s+=f; ss+=f*f;  f=bfhi(v.w); s+=f; ss+=f*f;
    }
  }
  __shared__ float rs[256], rss[256];
  rs[tid]=s; rss[tid]=ss; __syncthreads();
  for(int st=128; st>0; st>>=1){
    if(tid<st){ rs[tid]+=rs[tid+st]; rss[tid]+=rss[tid+st]; }
    __syncthreads();
  }
  if(tid==0){
    float n = (float)(16*4096);
    float mean = rs[0]/n;
    float var  = rss[0]/n - mean*mean;
    stats[o*2] = mean; stats[o*2+1] = rsqrtf(var + 1e-5f);
  }
}

// ---------- BN1 apply + relu + transpose -> y1b bf16 [b][p][c] ----------
__global__ void k_bn1_apply_t(const ushort* __restrict__ out1u, const float* __restrict__ stats,
                              const float* __restrict__ gamma, const float* __restrict__ beta,
                              ushort* __restrict__ y1b){
  __shared__ float ts[32][33];
  int tx = threadIdx.x & 31, ty = threadIdx.x >> 5;
  int p0 = blockIdx.x*32, o0 = blockIdx.y*32, b = blockIdx.z;
#pragma unroll
  for(int q=0;q<4;q++){
    int oo = ty + q*8; int o = o0 + oo;
    float m = stats[o*2], rstd = stats[o*2+1];
    float scale = rstd * gamma[o];
    float shift = beta[o] - m * scale;
    float v = bflo((unsigned)out1u[((size_t)(b*COUT+o)<<12) + p0+tx]);
    ts[oo][tx] = fmaxf(v*scale + shift, 0.f);
  }
  __syncthreads();
#pragma unroll
  for(int q=0;q<4;q++){
    int pr = ty + q*8;
    y1b[((size_t)(b*HW + p0+pr)<<8) + o0+tx] = f2bf(ts[tx][pr]);
  }
}

// ---------- conv-transpose MFMA v3: Mb=256 o, Nb=256 px, one (b,pp) ----------
// grid (16,4,4), 512 thr = 8 waves (2/SIMD). XCD-b affinity remap.
__global__ __launch_bounds__(512) void k_convt_mfma(const ushort* __restrict__ y1b,
                        const ushort* __restrict__ WT2c,
                        ushort* __restrict__ ct){
  __shared__ ushort Vs[2][256*LSTR2];   // 2 x 36864 B
  __shared__ int sIdx[1024];
  int tid = threadIdx.x;
  int fb  = blockIdx.x + (blockIdx.y<<4) + (blockIdx.z<<6);  // 0..255
  int jj = fb&7, rr2 = fb>>3;
  int b   = jj>>1;
  int pp  = ((rr2>>4)<<1) | (jj&1);
  int px0 = (rr2&15) << 8;
  int ph = pp>>1, pw = pp&1;

  for(int t=tid; t<1024; t+=512){
    int ab = t>>8, px = t&255;
    int a = ab>>1, bb = ab&1;
    int p = px0+px, r = p>>6, s = p&63;
    int ih = r + ph - 1 + a, iw = s + pw - 1 + bb;
    sIdx[t] = (ih>=0 && ih<64 && iw>=0 && iw<64) ? ((b*HW + ih*64+iw)<<8) : -1;
  }
  __syncthreads();

  int lane = tid&63, wv = tid>>6, lo = lane&15, hi = lane>>4;
  int om0 = (wv>>1)*64;
  int pn0 = (wv&1)*128;
  float4v acc[4][8];
#pragma unroll
  for(int i=0;i<4;i++)
#pragma unroll
    for(int j=0;j<8;j++) acc[i][j] = (float4v){0.f,0.f,0.f,0.f};

  const ushort* wbase = WT2c + ((size_t)pp<<18);
  const int wlaneb = (om0+lo)*32 + hi*8;
  int vpx = tid>>1, vseg = tid&1;
  uint4 vpre[4];

#define CT3_PREFETCH(PC) do{ \
    int kc0_ = (PC)*2; \
    int ab_ = kc0_>>3, c0_ = (kc0_&7)<<5; \
    int idx_ = sIdx[(ab_<<8) + vpx]; \
    int co_ = c0_ + vseg*32; \
    vpre[0]=make_uint4(0,0,0,0); vpre[1]=make_uint4(0,0,0,0); \
    vpre[2]=make_uint4(0,0,0,0); vpre[3]=make_uint4(0,0,0,0); \
    if(idx_ >= 0){ \
      vpre[0] = *(const uint4*)(y1b + idx_ + co_); \
      vpre[1] = *(const uint4*)(y1b + idx_ + co_ + 8); \
      vpre[2] = *(const uint4*)(y1b + idx_ + co_ + 16); \
      vpre[3] = *(const uint4*)(y1b + idx_ + co_ + 24); \
    } \
  }while(0)

#define CT3_WRITE(BUF) do{ \
    ushort* vp_ = &Vs[BUF][vpx*LSTR2 + vseg*32]; \
    *(uint4*)(vp_)      = vpre[0]; \
    *(uint4*)(vp_ + 8)  = vpre[1]; \
    *(uint4*)(vp_ + 16) = vpre[2]; \
    *(uint4*)(vp_ + 24) = vpre[3]; \
  }while(0)

  CT3_PREFETCH(0);
  CT3_WRITE(0);
  __syncthreads();

#pragma unroll 1
  for(int pc=0; pc<16; ++pc){
    int cur = pc&1;
    if(pc < 15) CT3_PREFETCH(pc+1);
#pragma unroll
    for(int c=0; c<2; ++c){
      const ushort* wp = wbase + ((size_t)(((pc<<1)|c))<<13) + wlaneb;
      const ushort* bp = &Vs[cur][(pn0+lo)*LSTR2 + c*32 + hi*8];
      short8 bfr[8];
#pragma unroll
      for(int j=0;j<8;j++) bfr[j] = *(const short8*)(bp + j*16*LSTR2);
#pragma unroll
      for(int i=0;i<4;i++){
        short8 afr = *(const short8*)(wp + i*512);
#pragma unroll
        for(int j=0;j<8;j++)
          acc[i][j] = __builtin_amdgcn_mfma_f32_16x16x32_bf16(afr, bfr[j], acc[i][j], 0,0,0);
      }
    }
    if(pc < 15) CT3_WRITE(cur^1);
    __syncthreads();
  }

  ushort* cb = ct + (((size_t)(pp*4 + b)*256)<<12);
#pragma unroll
  for(int i=0;i<4;i++){
#pragma unroll
    for(int r=0;r<4;r++){
      int o = om0 + i*16 + hi*4 + r;
      ushort* row = cb + ((size_t)o<<12) + px0 + pn0 + lo;
#pragma unroll
      for(int j=0;j<8;j++) row[j*16] = f2bf(acc[i][j][r]);
    }
  }
}

// ---------- BN2 apply + relu + parity interleave: ct bf16 -> out f32 ----------
__global__ void k_bn2_apply(const ushort* __restrict__ ct, const float* __restrict__ stats,
                            const float* __restrict__ gamma, const float* __restrict__ beta,
                            float* __restrict__ out){
  int gid = blockIdx.x*256 + threadIdx.x;   // grid 16384
  int e4 = gid<<2;
  int b = e4>>22, o = (e4>>14)&255, q = e4&16383;
  int H2 = q>>7, W2 = q&127;
  int r = H2>>1, ph = H2&1, s0 = W2>>1;
  size_t base0 = (((size_t)((ph*2)*4 + b)*256 + o)<<12) + r*64 + s0;
  unsigned u0 = *(const unsigned*)(ct + base0);
  unsigned u1 = *(const unsigned*)(ct + base0 + ((size_t)4<<20));
  float m = stats[o*2], rstd = stats[o*2+1];
  float sc = rstd * gamma[o];
  float sh = beta[o] - m * sc;
  float4 v;
  v.x = fmaxf(bflo(u0)*sc + sh, 0.f);
  v.y = fmaxf(bflo(u1)*sc + sh, 0.f);
  v.z = fmaxf(bfhi(u0)*sc + sh, 0.f);
  v.w = fmaxf(bfhi(u1)*sc + sh, 0.f);
  *(float4*)(out + e4) = v;
}

extern "C" void kernel_launch(void* const* d_in, const int* in_sizes, int n_in,
                              void* d_out, int out_size, void* d_ws, size_t ws_size,
                              hipStream_t stream){
  (void)in_sizes; (void)n_in; (void)out_size; (void)ws_size;
  const float* x     = (const float*)d_in[0];
  const float* w_off = (const float*)d_in[1];
  const float* b_off = (const float*)d_in[2];
  const float* w_dcn = (const float*)d_in[3];
  const float* gamma1= (const float*)d_in[5];
  const float* beta1 = (const float*)d_in[6];
  const float* w_up  = (const float*)d_in[7];
  const float* gamma2= (const float*)d_in[8];
  const float* beta2 = (const float*)d_in[9];
  float* out = (float*)d_out;

  // Workspace (floats). ct (bf16, 32 MB = 8388608 floats) aliases om2+xtb+out1u,
  // all of which are dead before k_convt_mfma runs.
  float* ws    = (float*)d_ws;
  ushort* ct   = (ushort*)ws;                      // [0, 8388608) floats
  float* om2   = ws;                               // 2x442368 = 884736 floats
  ushort* xtb  = (ushort*)(ws + 884736);           // 4194304 bf16 = 2097152 floats
  ushort* out1u= (ushort*)(ws + 884736 + 2097152); // 4194304 bf16 = 2097152 floats
                                                   // ends 5079040 <= 8388608
  float* base2 = ws + 8388608;
  ushort* y1b  = (ushort*)base2;                                   // 4194304 bf16
  ushort* WT2c = (ushort*)(base2 + 2097152);                       // 1048576 bf16
  ushort* Wdb  = (ushort*)(base2 + 2097152 + 524288);              // 589824 bf16
  ushort* Wob  = (ushort*)(base2 + 2097152 + 524288 + 294912);     // 73728 bf16
  float* st1   = base2 + 2097152 + 524288 + 294912 + 36864;        // 512
  float* st2   = st1 + 512;                                        // 512

  k_transpose_x <<<dim3(128,8,4), 256, 0, stream>>>(x, xtb);
  k_build_all   <<<6688, 256, 0, stream>>>(w_off, w_dcn, w_up, Wob, Wdb, WT2c);
  k_offset_mfma <<<dim3(64,4,2), 256, 0, stream>>>(xtb, Wob, om2);
  k_dcn_mfma    <<<dim3(64,4),   512, 0, stream>>>(xtb, om2, b_off, Wdb, out1u);
  k_bn_stats_bf1<<<256,  256, 0, stream>>>(out1u, st1);
  k_bn1_apply_t <<<dim3(128,8,4), 256, 0, stream>>>(out1u, st1, gamma1, beta1, y1b);
  k_convt_mfma  <<<dim3(16,4,4),  512, 0, stream>>>(y1b, WT2c, ct);
  k_bn_stats_ct <<<256,  256, 0, stream>>>(ct, st2);
  k_bn2_apply   <<<16384,256, 0, stream>>>(ct, st2, gamma2, beta2, out);
}